// Round 1
// baseline (635.333 us; speedup 1.0000x reference)
//
#include <hip/hip_runtime.h>
#include <stdint.h>

typedef unsigned short u16;
typedef __bf16 bf8 __attribute__((ext_vector_type(8)));
typedef float f32x4 __attribute__((ext_vector_type(4)));

#define SEQ 2048
#define HIDDEN 4096
#define DQKV 6144   // 48 heads * 128
#define HD 128

// async global->LDS, 16B/lane. LDS dest is wave-uniform base + lane*16 (m104/m108);
// all staging layouts below are laid out so lane l's element lands at base + l*16B.
#define GLOAD_LDS16(g, l)                                                            \
    __builtin_amdgcn_global_load_lds((const __attribute__((address_space(1))) void*)(g), \
                                     (__attribute__((address_space(3))) void*)(l), 16, 0, 0)

__device__ __forceinline__ u16 f2bf(float f) {
    union { float f; unsigned u; } v{f};
    unsigned r = (v.u + 0x7fff + ((v.u >> 16) & 1)) >> 16;
    return (u16)r;
}
__device__ __forceinline__ float bf2f(u16 b) {
    union { unsigned u; float f; } v;
    v.u = ((unsigned)b) << 16;
    return v.f;
}

// ---------------- pre-pass kernels ----------------

__global__ void convert_bf16_kernel(const float* __restrict__ in, u16* __restrict__ out) {
    int i = (blockIdx.x * 256 + threadIdx.x) * 4;
    float4 v = *(const float4*)(in + i);
    u16 o[4] = {f2bf(v.x), f2bf(v.y), f2bf(v.z), f2bf(v.w)};
    *(uint2*)(out + i) = *(uint2*)o;
}

// in fp32 [K][N] -> out bf16 [N][K]
__global__ void transpose_w_kernel(const float* __restrict__ in, u16* __restrict__ out, int K, int N) {
    __shared__ u16 tile[64][65];
    int tn = N >> 6;
    int bk = blockIdx.x / tn, bn = blockIdx.x % tn;
    int k0 = bk * 64, n0 = bn * 64;
    int c = threadIdx.x & 63, r0 = threadIdx.x >> 6;
#pragma unroll
    for (int r = r0; r < 64; r += 4)
        tile[r][c] = f2bf(in[(size_t)(k0 + r) * N + n0 + c]);
    __syncthreads();
#pragma unroll
    for (int r = r0; r < 64; r += 4)
        out[(size_t)(n0 + r) * K + k0 + c] = tile[c][r];
}

// RoPE in-place on Q/K heads (0..39) of xqkv [2048][6144]
__global__ void rope_kernel(u16* __restrict__ x) {
    const int row = blockIdx.x / 10, hg = blockIdx.x % 10;
    const int head = hg * 4 + (threadIdx.x >> 6), j = threadIdx.x & 63;
    u16* p = x + (size_t)row * DQKV + head * HD + j;
    float x1 = bf2f(p[0]), x2 = bf2f(p[64]);
    float inv = exp2f(-(float)j * 0.20762050593045952f); // log2(10000)/64
    float s, c;
    sincosf((float)row * inv, &s, &c);
    p[0] = f2bf(x1 * c - x2 * s);
    p[64] = f2bf(x1 * s + x2 * c);
}

// V heads (40..47) of xqkv [2048][6144] -> VT [8][128][2048]
__global__ void transpose_v_kernel(const u16* __restrict__ xqkv, u16* __restrict__ vt) {
    __shared__ u16 tile[64][65];
    int h = blockIdx.x >> 6;
    int t = blockIdx.x & 63;
    int s0 = (t >> 1) * 64, d0 = (t & 1) * 64;
    int c = threadIdx.x & 63, r0 = threadIdx.x >> 6;
    const u16* src = xqkv + (40 + h) * HD + d0;
#pragma unroll
    for (int r = r0; r < 64; r += 4)
        tile[r][c] = src[(size_t)(s0 + r) * DQKV + c];
    __syncthreads();
    u16* dst = vt + ((size_t)h * HD + d0) * SEQ + s0;
#pragma unroll
    for (int r = r0; r < 64; r += 4)
        dst[(size_t)r * SEQ + c] = tile[c][r];
}

// ---------------- GEMM: C[M][*] = A[M][4096] * BT[N][4096]^T ----------------
// 256x256-tile, BK=64, 8 waves (2M x 4N), 512 threads, 8-phase schedule
// (m201 template: T2 st_16x32 swizzle + T4 counted vmcnt + T5 setprio).
// LDS 128 KiB = 2 K-tile dbuf x 4 half-tiles (A0,A1,B0,B1) x 128x64 bf16.
// Staging: global_load_lds writes LINEAR (base + lane*16); the st_16x32 swizzle
// (byte ^= ((byte>>9)&1)<<5, bit9 == row-bit2, bit5 lives in the col field) is
// applied by PRE-SWIZZLING the per-lane global source col, and again on the
// ds_read address (rule #21: both-sides-or-neither).
// Per K-tile: 4 quadrant phases (m0n0)->(m0n1)->(m1n1)->(m1n0), frag loads
// 12/4/8/0 ds_read_b128 (minimal 24/K-tile). Each phase: loads; s_barrier;
// lgkmcnt(0); setprio(1); 16 MFMA; setprio(0); s_barrier.
// Boundary: stage K-tile t+2 into the just-drained buffer (safe: all frag reads
// were MFMA-consumed -> lgkm drained before the last phase barrier), then
// s_waitcnt vmcnt(8) -- next tile's 8 loads stay in flight across the barrier.
template <int MODE>  // MODE 0: N=6144, bf16 out (XQKV). MODE 1: N=4096, f32 out.
__global__ __launch_bounds__(512, 2) void gemm8p_kernel(const u16* __restrict__ A,
                                                        const u16* __restrict__ BT,
                                                        u16* __restrict__ Cbf,
                                                        float* __restrict__ Cf) {
    constexpr int NBT = (MODE == 0) ? 24 : 16;
    constexpr int CSTR = (MODE == 0) ? DQKV : HIDDEN;
    constexpr int NT = 4096 / 64;   // 64 K-tiles
    __shared__ u16 lds[2][4][8192]; // [buf][half: A0,A1,B0,B1][128*64]
    const int tid = threadIdx.x;
    const int w = tid >> 6, l = tid & 63, l15 = l & 15, q4 = l >> 4;
    const int wm = w >> 2, wn = w & 3;
    const int bm = blockIdx.x / NBT, bn = blockIdx.x % NBT;

    // staging source pointers: thread covers LDS bytes [tid*16 + i*8192, +16)
    // of each half-tile => logical row r0+i*64, col ((tid&7)*16) ^ swz(bit9=tid bit5)
    const char* sp[8];
    {
        const int r0 = tid >> 3;
        const int cb = ((tid & 7) << 4) ^ (((tid >> 5) & 1) << 5);
#pragma unroll
        for (int h = 0; h < 4; ++h)
#pragma unroll
            for (int i = 0; i < 2; ++i) {
                const u16* base = (h < 2)
                    ? A + (size_t)(bm * 256 + h * 128 + r0 + i * 64) * 4096
                    : BT + (size_t)(bn * 256 + (h - 2) * 128 + r0 + i * 64) * 4096;
                sp[h * 2 + i] = (const char*)base + cb;
            }
    }

#define STAGE8(b)                                                                  \
    do {                                                                           \
        _Pragma("unroll") for (int h = 0; h < 4; ++h)                              \
            _Pragma("unroll") for (int i = 0; i < 2; ++i)                          \
                GLOAD_LDS16(sp[h * 2 + i], &lds[b][h][w * 512 + i * 4096]);        \
        _Pragma("unroll") for (int j = 0; j < 8; ++j) sp[j] += 128;                \
    } while (0)

    f32x4 acc[8][4] = {};

    // prologue: stage tiles 0 and 1; wait tile 0 (8 of 16 loads outstanding ok)
    STAGE8(0);
    STAGE8(1);
    asm volatile("s_waitcnt vmcnt(8)" ::: "memory");
    asm volatile("s_barrier" ::: "memory");

    const int smask = ((l15 >> 2) & 1) << 5;   // st_16x32 read-side swizzle
    const int c0 = (q4 * 16) ^ smask;          // kslice 0 col-byte
    const int c1 = (64 + q4 * 16) ^ smask;     // kslice 1 col-byte
    const int lrb = (wn & 1) * 64;             // B local row base within half

#pragma unroll 1
    for (int tt = 0; tt < NT; tt += 2) {
#pragma unroll
        for (int half = 0; half < 2; ++half) {
            const int t = tt + half;
            const int cur = half;  // buffers strictly alternate from 0
            const char* ha = (const char*)&lds[cur][wm][0];
            const char* hb = (const char*)&lds[cur][2 + (wn >> 1)][0];
            bf8 a[4][2], b0[2][2], b1[2][2];

            // ---- phase 0: load A[m0..3] (8) + B[n0..1] (4); mfma m0..3 x n0..1
#pragma unroll
            for (int mf = 0; mf < 4; ++mf) {
                const int lr = mf * 16 + l15;
                a[mf][0] = *(const bf8*)(ha + lr * 128 + c0);
                a[mf][1] = *(const bf8*)(ha + lr * 128 + c1);
            }
#pragma unroll
            for (int nf = 0; nf < 2; ++nf) {
                const int lr = lrb + nf * 16 + l15;
                b0[nf][0] = *(const bf8*)(hb + lr * 128 + c0);
                b0[nf][1] = *(const bf8*)(hb + lr * 128 + c1);
            }
            asm volatile("s_barrier" ::: "memory");
            asm volatile("s_waitcnt lgkmcnt(0)" ::: "memory");
            __builtin_amdgcn_s_setprio(1);
#pragma unroll
            for (int mf = 0; mf < 4; ++mf)
#pragma unroll
                for (int nf = 0; nf < 2; ++nf)
#pragma unroll
                    for (int ks = 0; ks < 2; ++ks)
                        acc[mf][nf] = __builtin_amdgcn_mfma_f32_16x16x32_bf16(
                            a[mf][ks], b0[nf][ks], acc[mf][nf], 0, 0, 0);
            __builtin_amdgcn_s_setprio(0);
            asm volatile("s_barrier" ::: "memory");

            // ---- phase 1: load B[n2..3] (4); mfma m0..3 x n2..3
#pragma unroll
            for (int nf = 0; nf < 2; ++nf) {
                const int lr = lrb + (2 + nf) * 16 + l15;
                b1[nf][0] = *(const bf8*)(hb + lr * 128 + c0);
                b1[nf][1] = *(const bf8*)(hb + lr * 128 + c1);
            }
            asm volatile("s_barrier" ::: "memory");
            asm volatile("s_waitcnt lgkmcnt(0)" ::: "memory");
            __builtin_amdgcn_s_setprio(1);
#pragma unroll
            for (int mf = 0; mf < 4; ++mf)
#pragma unroll
                for (int nf = 0; nf < 2; ++nf)
#pragma unroll
                    for (int ks = 0; ks < 2; ++ks)
                        acc[mf][2 + nf] = __builtin_amdgcn_mfma_f32_16x16x32_bf16(
                            a[mf][ks], b1[nf][ks], acc[mf][2 + nf], 0, 0, 0);
            __builtin_amdgcn_s_setprio(0);
            asm volatile("s_barrier" ::: "memory");

            // ---- phase 2: load A[m4..7] (8); mfma m4..7 x n2..3
#pragma unroll
            for (int mf = 0; mf < 4; ++mf) {
                const int lr = (4 + mf) * 16 + l15;
                a[mf][0] = *(const bf8*)(ha + lr * 128 + c0);
                a[mf][1] = *(const bf8*)(ha + lr * 128 + c1);
            }
            asm volatile("s_barrier" ::: "memory");
            asm volatile("s_waitcnt lgkmcnt(0)" ::: "memory");
            __builtin_amdgcn_s_setprio(1);
#pragma unroll
            for (int mf = 0; mf < 4; ++mf)
#pragma unroll
                for (int nf = 0; nf < 2; ++nf)
#pragma unroll
                    for (int ks = 0; ks < 2; ++ks)
                        acc[4 + mf][2 + nf] = __builtin_amdgcn_mfma_f32_16x16x32_bf16(
                            a[mf][ks], b1[nf][ks], acc[4 + mf][2 + nf], 0, 0, 0);
            __builtin_amdgcn_s_setprio(0);
            asm volatile("s_barrier" ::: "memory");

            // ---- phase 3: no loads; mfma m4..7 x n0..1 (b0 still live)
            __builtin_amdgcn_s_setprio(1);
#pragma unroll
            for (int mf = 0; mf < 4; ++mf)
#pragma unroll
                for (int nf = 0; nf < 2; ++nf)
#pragma unroll
                    for (int ks = 0; ks < 2; ++ks)
                        acc[4 + mf][nf] = __builtin_amdgcn_mfma_f32_16x16x32_bf16(
                            a[mf][ks], b0[nf][ks], acc[4 + mf][nf], 0, 0, 0);
            __builtin_amdgcn_s_setprio(0);
            asm volatile("s_barrier" ::: "memory");

            // ---- K-tile boundary: stage t+2 into the buffer just drained,
            // counted vmcnt keeps t+2's 8 loads in flight across the barrier.
            if (t < NT - 2) {
                STAGE8(cur);
                asm volatile("s_waitcnt vmcnt(8)" ::: "memory");
            } else if (t == NT - 2) {
                asm volatile("s_waitcnt vmcnt(0)" ::: "memory");
            }
            asm volatile("s_barrier" ::: "memory");
        }
    }
#undef STAGE8

    const int rowb = bm * 256 + wm * 128;
    const int colb = bn * 256 + wn * 64;
#pragma unroll
    for (int mf = 0; mf < 8; ++mf)
#pragma unroll
        for (int nf = 0; nf < 4; ++nf)
#pragma unroll
            for (int r = 0; r < 4; ++r) {
                const int row = rowb + mf * 16 + q4 * 4 + r;
                const int col = colb + nf * 16 + l15;
                if constexpr (MODE == 0)
                    Cbf[(size_t)row * CSTR + col] = f2bf(acc[mf][nf][r]);
                else
                    Cf[(size_t)row * CSTR + col] = acc[mf][nf][r];
            }
}

// ---------------- flash attention ----------------
// grid: 512 = 16 q-tiles * 32 heads. block 256 = 4 waves, each wave owns 32 Q rows.
// No running max (scores bounded: |s|<~20 -> exp2 stays in fp32/bf16 range), so
// softmax = unnormalized p=exp2(s*cs), per-lane row-sum accumulated in registers,
// single shuffle-reduce + normalize at the end.
#define PSTR 72   // P row stride in shorts: 64 cols + 8 pad (2-way bank alias = free)
__global__ __launch_bounds__(256) void attn_kernel(const u16* __restrict__ xqkv,
                                                   const u16* __restrict__ vt,
                                                   u16* __restrict__ aw) {
    // smem layout (shorts): [0,8192) K [4][64][32]; [8192,16384) V [2][128][32];
    // [16384,16384+128*PSTR) P [128][PSTR].  Q staged once at [0,16384) then reused.
    __shared__ __align__(16) u16 sm[16384 + 128 * PSTR];
    const int tid = threadIdx.x, w = tid >> 6, l = tid & 63, l15 = l & 15, q4 = l >> 4;
    const int qh = blockIdx.x & 31;
    const int qslot = blockIdx.x >> 5;
    // complementary pairing: blocks b and b+256 get qt summing to 15 (tail balance)
    const int qt = (qslot < 8) ? qslot : 23 - qslot;
    const int kh = qh >> 2;

    { // stage Q tile: [ks=w][row 128][32], async
        const u16* gq = xqkv + (size_t)(qt * 128 + (l >> 2)) * DQKV + qh * HD + w * 32 + (l & 3) * 8;
#pragma unroll
        for (int i = 0; i < 8; ++i)
            GLOAD_LDS16(gq + (size_t)i * 16 * DQKV, &sm[w * 4096 + i * 512]);
    }
    __syncthreads();
    bf8 qf[4][2];
#pragma unroll
    for (int ks = 0; ks < 4; ++ks)
#pragma unroll
        for (int mt = 0; mt < 2; ++mt)
            qf[ks][mt] = *(const bf8*)&sm[ks * 4096 + (w * 32 + mt * 16 + l15) * 32 + q4 * 8];
    __syncthreads();

    f32x4 O[2][8] = {};
    float plrow[2][4] = {};   // per-lane unnormalized row-sum partials

    u16* ldsK = sm;
    u16* ldsV = sm + 8192;
    u16* ldsP = sm + 16384;
    const int nkt = 2 * qt + 2;
    const float cs = 0.12751744f; // (1/sqrt(128)) * log2(e)

    const u16* gk_base = xqkv + (32 + kh) * HD + w * 32 + (l & 3) * 8;
    const u16* gv_base = vt + (size_t)kh * HD * SEQ + (size_t)((w & 1) * 64 + (l >> 2)) * SEQ + (w >> 1) * 32 + (l & 3) * 8;

    for (int kt = 0; kt < nkt; ++kt) {
        { // stage K: wave w owns k-chunk ks=w  (async, lane-contiguous)
            const u16* gk = gk_base + (size_t)(kt * 64 + (l >> 2)) * DQKV;
#pragma unroll
            for (int i = 0; i < 4; ++i)
                GLOAD_LDS16(gk + (size_t)i * 16 * DQKV, ldsK + w * 2048 + i * 512);
        }
        { // stage V^T: wave w owns pk=w>>1, d-half=(w&1)*64
            const u16* gv = gv_base + kt * 64;
#pragma unroll
            for (int i = 0; i < 4; ++i)
                GLOAD_LDS16(gv + (size_t)i * 16 * SEQ, ldsV + (w >> 1) * 4096 + (w & 1) * 2048 + i * 512);
        }
        __syncthreads();   // drains vmcnt

        // S = Q K^T
        f32x4 S[2][4] = {};
#pragma unroll
        for (int ks = 0; ks < 4; ++ks) {
            bf8 kf[4];
#pragma unroll
            for (int nt = 0; nt < 4; ++nt)
                kf[nt] = *(const bf8*)&ldsK[ks * 2048 + (nt * 16 + l15) * 32 + q4 * 8];
#pragma unroll
            for (int mt = 0; mt < 2; ++mt)
#pragma unroll
                for (int nt = 0; nt < 4; ++nt)
                    S[mt][nt] = __builtin_amdgcn_mfma_f32_16x16x32_bf16(qf[ks][mt], kf[nt], S[mt][nt], 0, 0, 0);
        }

        const bool domask = (kt >= 2 * qt);
#pragma unroll
        for (int mt = 0; mt < 2; ++mt)
#pragma unroll
            for (int r = 0; r < 4; ++r) {
                const int row = qt * 128 + w * 32 + mt * 16 + q4 * 4 + r;
#pragma unroll
                for (int nt = 0; nt < 4; ++nt) {
                    float t = S[mt][nt][r] * cs;
                    if (domask && (kt * 64 + nt * 16 + l15 > row)) t = -1e30f;
                    float p = exp2f(t);
                    plrow[mt][r] += p;
                    ldsP[(w * 32 + mt * 16 + q4 * 4 + r) * PSTR + nt * 16 + l15] = f2bf(p);
                }
            }

        // O += P V   (P rows are wave-private: no barrier needed)
#pragma unroll
        for (int pk = 0; pk < 2; ++pk) {
            bf8 pf[2], vf[8];
#pragma unroll
            for (int mt = 0; mt < 2; ++mt)
                pf[mt] = *(const bf8*)&ldsP[(w * 32 + mt * 16 + l15) * PSTR + pk * 32 + q4 * 8];
#pragma unroll
            for (int nt = 0; nt < 8; ++nt)
                vf[nt] = *(const bf8*)&ldsV[pk * 4096 + (nt * 16 + l15) * 32 + q4 * 8];
#pragma unroll
            for (int mt = 0; mt < 2; ++mt)
#pragma unroll
                for (int nt = 0; nt < 8; ++nt)
                    O[mt][nt] = __builtin_amdgcn_mfma_f32_16x16x32_bf16(pf[mt], vf[nt], O[mt][nt], 0, 0, 0);
        }
        __syncthreads();   // all waves done reading K/V/P before next stage
    }

#pragma unroll
    for (int mt = 0; mt < 2; ++mt)
#pragma unroll
        for (int r = 0; r < 4; ++r) {
            float ls = plrow[mt][r];   // row-sum lives across the 16 lanes of this q4 group
#pragma unroll
            for (int off = 1; off <= 8; off <<= 1)
                ls += __shfl_xor(ls, off, 64);
            const float linv = 1.0f / ls;
            const int row = qt * 128 + w * 32 + mt * 16 + q4 * 4 + r;
#pragma unroll
            for (int nt = 0; nt < 8; ++nt)
                aw[(size_t)row * 4096 + qh * HD + nt * 16 + l15] = f2bf(O[mt][nt][r] * linv);
        }
}

// ---------------- launch ----------------

extern "C" void kernel_launch(void* const* d_in, const int* in_sizes, int n_in,
                              void* d_out, int out_size, void* d_ws, size_t ws_size,
                              hipStream_t stream) {
    const float* hs = (const float*)d_in[0];
    const float* wqkv = (const float*)d_in[1];
    const float* wo = (const float*)d_in[2];
    float* out = (float*)d_out;

    char* ws = (char*)d_ws;
    const size_t oHbf = 0;
    const size_t oWqkvT = oHbf + (size_t)SEQ * HIDDEN * 2;          // 16.78 MB
    const size_t oWoT = oWqkvT + (size_t)DQKV * HIDDEN * 2;         // +50.33 MB
    const size_t oXQKV = oWoT + (size_t)HIDDEN * HIDDEN * 2;        // +33.55 MB
    const size_t oVT = oXQKV + (size_t)SEQ * DQKV * 2;              // +25.17 MB
    const size_t oAW = oVT + (size_t)8 * HD * SEQ * 2;              // +4.19 MB
    const size_t total = oAW + (size_t)SEQ * HIDDEN * 2;            // +16.78 MB = 146.8 MB
    if (ws_size < total) return;

    u16* Hbf = (u16*)(ws + oHbf);
    u16* WqkvT = (u16*)(ws + oWqkvT);
    u16* WoT = (u16*)(ws + oWoT);
    u16* XQKV = (u16*)(ws + oXQKV);
    u16* VT = (u16*)(ws + oVT);
    u16* AW = (u16*)(ws + oAW);

    convert_bf16_kernel<<<(SEQ * HIDDEN) / 1024, 256, 0, stream>>>(hs, Hbf);
    transpose_w_kernel<<<(HIDDEN / 64) * (DQKV / 64), 256, 0, stream>>>(wqkv, WqkvT, HIDDEN, DQKV);
    transpose_w_kernel<<<(HIDDEN / 64) * (HIDDEN / 64), 256, 0, stream>>>(wo, WoT, HIDDEN, HIDDEN);
    gemm8p_kernel<0><<<8 * 24, 512, 0, stream>>>(Hbf, WqkvT, XQKV, nullptr);   // 192 blocks, 1/CU
    rope_kernel<<<SEQ * 10, 256, 0, stream>>>(XQKV);
    transpose_v_kernel<<<8 * 64, 256, 0, stream>>>(XQKV, VT);
    attn_kernel<<<512, 256, 0, stream>>>(XQKV, VT, AW);
    gemm8p_kernel<1><<<8 * 16, 512, 0, stream>>>(AW, WoT, nullptr, out);
}

// Round 2
// 519.258 us; speedup vs baseline: 1.2235x; 1.2235x over previous
//
#include <hip/hip_runtime.h>
#include <stdint.h>

typedef unsigned short u16;
typedef __bf16 bf8 __attribute__((ext_vector_type(8)));
typedef float f32x4 __attribute__((ext_vector_type(4)));

#define SEQ 2048
#define HIDDEN 4096
#define DQKV 6144   // 48 heads * 128
#define HD 128

// async global->LDS, 16B/lane. LDS dest is wave-uniform base + lane*16 (m104/m108);
// all staging layouts below are laid out so lane l's element lands at base + l*16B.
#define GLOAD_LDS16(g, l)                                                            \
    __builtin_amdgcn_global_load_lds((const __attribute__((address_space(1))) void*)(g), \
                                     (__attribute__((address_space(3))) void*)(l), 16, 0, 0)

__device__ __forceinline__ u16 f2bf(float f) {
    union { float f; unsigned u; } v{f};
    unsigned r = (v.u + 0x7fff + ((v.u >> 16) & 1)) >> 16;
    return (u16)r;
}
__device__ __forceinline__ float bf2f(u16 b) {
    union { unsigned u; float f; } v;
    v.u = ((unsigned)b) << 16;
    return v.f;
}

// ---------------- pre-pass kernels ----------------

__global__ void convert_bf16_kernel(const float* __restrict__ in, u16* __restrict__ out) {
    int i = (blockIdx.x * 256 + threadIdx.x) * 4;
    float4 v = *(const float4*)(in + i);
    u16 o[4] = {f2bf(v.x), f2bf(v.y), f2bf(v.z), f2bf(v.w)};
    *(uint2*)(out + i) = *(uint2*)o;
}

// in fp32 [K][N] -> out bf16 [N][K]
__global__ void transpose_w_kernel(const float* __restrict__ in, u16* __restrict__ out, int K, int N) {
    __shared__ u16 tile[64][65];
    int tn = N >> 6;
    int bk = blockIdx.x / tn, bn = blockIdx.x % tn;
    int k0 = bk * 64, n0 = bn * 64;
    int c = threadIdx.x & 63, r0 = threadIdx.x >> 6;
#pragma unroll
    for (int r = r0; r < 64; r += 4)
        tile[r][c] = f2bf(in[(size_t)(k0 + r) * N + n0 + c]);
    __syncthreads();
#pragma unroll
    for (int r = r0; r < 64; r += 4)
        out[(size_t)(n0 + r) * K + k0 + c] = tile[c][r];
}

// RoPE in-place on Q/K heads (0..39) of xqkv [2048][6144]
__global__ void rope_kernel(u16* __restrict__ x) {
    const int row = blockIdx.x / 10, hg = blockIdx.x % 10;
    const int head = hg * 4 + (threadIdx.x >> 6), j = threadIdx.x & 63;
    u16* p = x + (size_t)row * DQKV + head * HD + j;
    float x1 = bf2f(p[0]), x2 = bf2f(p[64]);
    float inv = exp2f(-(float)j * 0.20762050593045952f); // log2(10000)/64
    float s, c;
    sincosf((float)row * inv, &s, &c);
    p[0] = f2bf(x1 * c - x2 * s);
    p[64] = f2bf(x1 * s + x2 * c);
}

// V heads (40..47) of xqkv [2048][6144] -> VT [8][128][2048]
__global__ void transpose_v_kernel(const u16* __restrict__ xqkv, u16* __restrict__ vt) {
    __shared__ u16 tile[64][65];
    int h = blockIdx.x >> 6;
    int t = blockIdx.x & 63;
    int s0 = (t >> 1) * 64, d0 = (t & 1) * 64;
    int c = threadIdx.x & 63, r0 = threadIdx.x >> 6;
    const u16* src = xqkv + (40 + h) * HD + d0;
#pragma unroll
    for (int r = r0; r < 64; r += 4)
        tile[r][c] = src[(size_t)(s0 + r) * DQKV + c];
    __syncthreads();
    u16* dst = vt + ((size_t)h * HD + d0) * SEQ + s0;
#pragma unroll
    for (int r = r0; r < 64; r += 4)
        dst[(size_t)r * SEQ + c] = tile[c][r];
}

// ---------------- GEMM: C[M][*] = A[M][4096] * BT[N][4096]^T ----------------
// 8-phase-family schedule, grid exactly 256 blocks (1/CU), 8 waves (2M x 4N).
// MODE 0: 256x192 tile (8x32 grid), bf16 out stride 6144.
// MODE 1: 128x256 tile (16x16 grid), f32 out stride 4096.
// LDS: 2 buffers x [A BM rows | B BN rows] x 64 cols bf16, 128-byte rows.
// Swizzle (T2, corrected): logical (r,c) stored at phys c ^ ((r&7)<<4) -- rows
// 0..7 cover all eight 16B slots -> all 32 banks, 2 lanes/slot (free, m136).
// global_load_lds writes linear, so the SOURCE column is pre-permuted with the
// same involution: src col = ((tid&7)^((tid>>3)&7))<<4 (rule #21).
// Per K-tile: 4 phases, each {stage-issue || ds_read A-frag pair -> barrier ->
// lgkmcnt(0) -> setprio(1) -> MFMA cluster -> setprio(0) -> barrier}. N-side
// fragments are read once (phase 0) and held in registers for the whole K-tile.
// Staging of tile t+2 goes into the CURRENT buffer as regions die: B lines at
// p1 (B read only in p0), early-dead A lines at p2, rest at the boundary, then
// counted vmcnt(NL) (7 or 6, never 0 in steady state) + barrier.
template <int BM, int BN, int MODE>
__global__ __launch_bounds__(512, 2) void gemm8p_kernel(const u16* __restrict__ A,
                                                        const u16* __restrict__ BT,
                                                        u16* __restrict__ Cbf,
                                                        float* __restrict__ Cf) {
    constexpr int WM = BM / 32;          // m-frags per wave
    constexpr int WN = BN / 64;          // n-frags per wave
    constexpr int MP = WM / 4;           // m-frags per phase
    constexpr int NLA = BM / 64, NLB = BN / 64, NL = NLA + NLB;
    constexpr int NBN = ((MODE == 0) ? DQKV : HIDDEN) / BN;
    constexpr int CSTR = (MODE == 0) ? DQKV : HIDDEN;
    constexpr int NT = 64;               // K / 64
    __shared__ __align__(16) u16 lds[2][(BM + BN) * 64];

    const int tid = threadIdx.x;
    const int w = tid >> 6, l = tid & 63, l15 = l & 15, q4 = l >> 4;
    const int wm = w >> 2, wn = w & 3;
    const int bm = blockIdx.x / NBN, bn = blockIdx.x % NBN;

    // staging: thread tid fills phys bytes [line*8192 + tid*16, +16) of a region
    // = logical row line*64 + tid/8, col ((tid&7)^((tid>>3)&7))*16 (swizzled src)
    const int srow = tid >> 3;
    const int scol = ((tid & 7) ^ ((tid >> 3) & 7)) << 4;
    const char* spA[NLA];
    const char* spB[NLB];
#pragma unroll
    for (int L = 0; L < NLA; ++L)
        spA[L] = (const char*)(A + (size_t)(bm * BM + L * 64 + srow) * 4096) + scol;
#pragma unroll
    for (int L = 0; L < NLB; ++L)
        spB[L] = (const char*)(BT + (size_t)(bn * BN + L * 64 + srow) * 4096) + scol;

#define STG_A(L, tt, b) GLOAD_LDS16(spA[L] + (size_t)(tt) * 128, &lds[b][(L) * 4096 + w * 512])
#define STG_B(L, tt, b) GLOAD_LDS16(spB[L] + (size_t)(tt) * 128, &lds[b][BM * 64 + (L) * 4096 + w * 512])

    // prologue: stage tiles 0 and 1, wait for tile 0 only (NL of tile 1 in flight)
#pragma unroll
    for (int L = 0; L < NLA; ++L) STG_A(L, 0, 0);
#pragma unroll
    for (int L = 0; L < NLB; ++L) STG_B(L, 0, 0);
#pragma unroll
    for (int L = 0; L < NLA; ++L) STG_A(L, 1, 1);
#pragma unroll
    for (int L = 0; L < NLB; ++L) STG_B(L, 1, 1);
    if constexpr (NL == 7) asm volatile("s_waitcnt vmcnt(7)" ::: "memory");
    else                   asm volatile("s_waitcnt vmcnt(6)" ::: "memory");
    asm volatile("s_barrier" ::: "memory");

    // read-side swizzle: frag row = 16*frag + l15 -> row&7 == l15&7
    const int c0x = (q4 * 16) ^ ((l15 & 7) << 4);
    const int c1x = (64 + q4 * 16) ^ ((l15 & 7) << 4);

    f32x4 acc[WM][WN] = {};
    bf8 breg[WN][2];

#pragma unroll 1
    for (int t = 0; t < NT; ++t) {
        const int cur = t & 1;
        const char* ldsA = (const char*)&lds[cur][0];
        const char* ldsB = ldsA + BM * 128;
#pragma unroll
        for (int p = 0; p < 4; ++p) {
            // stage tile t+2 into the regions of buf[cur] that died last phase
            if (p == 1 && t < NT - 2) {
#pragma unroll
                for (int L = 0; L < NLB; ++L) STG_B(L, t + 2, cur);
            }
            if constexpr (BM == 256) {
                // A lines 0,2 (rows 0-63 of each wm-half) are read only in p0/p1
                if (p == 2 && t < NT - 2) {
                    STG_A(0, t + 2, cur);
                    STG_A(2, t + 2, cur);
                }
            }
            bf8 areg[MP][2];
#pragma unroll
            for (int j = 0; j < MP; ++j) {
                const char* rp = ldsA + (wm * (BM / 2) + (p * MP + j) * 16 + l15) * 128;
                areg[j][0] = *(const bf8*)(rp + c0x);
                areg[j][1] = *(const bf8*)(rp + c1x);
            }
            if (p == 0) {
#pragma unroll
                for (int nf = 0; nf < WN; ++nf) {
                    const char* rp = ldsB + (wn * (WN * 16) + nf * 16 + l15) * 128;
                    breg[nf][0] = *(const bf8*)(rp + c0x);
                    breg[nf][1] = *(const bf8*)(rp + c1x);
                }
            }
            asm volatile("s_barrier" ::: "memory");
            asm volatile("s_waitcnt lgkmcnt(0)" ::: "memory");
            __builtin_amdgcn_s_setprio(1);
#pragma unroll
            for (int j = 0; j < MP; ++j)
#pragma unroll
                for (int nf = 0; nf < WN; ++nf)
#pragma unroll
                    for (int ks = 0; ks < 2; ++ks)
                        acc[p * MP + j][nf] = __builtin_amdgcn_mfma_f32_16x16x32_bf16(
                            areg[j][ks], breg[nf][ks], acc[p * MP + j][nf], 0, 0, 0);
            __builtin_amdgcn_s_setprio(0);
            asm volatile("s_barrier" ::: "memory");
        }
        // boundary: stage the A lines that stayed live through p3, then counted
        // vmcnt -- guarantees tile t+1 (issued during t-1) fully landed, while
        // tile t+2's NL loads stay in flight across the barrier.
        if (t < NT - 2) {
            if constexpr (BM == 256) { STG_A(1, t + 2, cur); STG_A(3, t + 2, cur); }
            else                     { STG_A(0, t + 2, cur); STG_A(1, t + 2, cur); }
            if constexpr (NL == 7) asm volatile("s_waitcnt vmcnt(7)" ::: "memory");
            else                   asm volatile("s_waitcnt vmcnt(6)" ::: "memory");
        } else if (t == NT - 2) {
            asm volatile("s_waitcnt vmcnt(0)" ::: "memory");
        }
        asm volatile("s_barrier" ::: "memory");
    }
#undef STG_A
#undef STG_B

    const int rowb = bm * BM + wm * (BM / 2);
    const int colb = bn * BN + wn * (WN * 16);
#pragma unroll
    for (int mf = 0; mf < WM; ++mf)
#pragma unroll
        for (int nf = 0; nf < WN; ++nf)
#pragma unroll
            for (int r = 0; r < 4; ++r) {
                const int row = rowb + mf * 16 + q4 * 4 + r;
                const int col = colb + nf * 16 + l15;
                if constexpr (MODE == 0)
                    Cbf[(size_t)row * CSTR + col] = f2bf(acc[mf][nf][r]);
                else
                    Cf[(size_t)row * CSTR + col] = acc[mf][nf][r];
            }
}

// ---------------- flash attention ----------------
// grid: 512 = 16 q-tiles * 32 heads. block 256 = 4 waves, each wave owns 32 Q rows.
// No running max (scores bounded: |s|<~20 -> exp2 stays in fp32/bf16 range), so
// softmax = unnormalized p=exp2(s*cs), per-lane row-sum accumulated in registers,
// single shuffle-reduce + normalize at the end.
#define PSTR 72   // P row stride in shorts: 64 cols + 8 pad (2-way bank alias = free)
__global__ __launch_bounds__(256) void attn_kernel(const u16* __restrict__ xqkv,
                                                   const u16* __restrict__ vt,
                                                   u16* __restrict__ aw) {
    // smem layout (shorts): [0,8192) K [4][64][32]; [8192,16384) V [2][128][32];
    // [16384,16384+128*PSTR) P [128][PSTR].  Q staged once at [0,16384) then reused.
    __shared__ __align__(16) u16 sm[16384 + 128 * PSTR];
    const int tid = threadIdx.x, w = tid >> 6, l = tid & 63, l15 = l & 15, q4 = l >> 4;
    const int qh = blockIdx.x & 31;
    const int qslot = blockIdx.x >> 5;
    // complementary pairing: blocks b and b+256 get qt summing to 15 (tail balance)
    const int qt = (qslot < 8) ? qslot : 23 - qslot;
    const int kh = qh >> 2;

    { // stage Q tile: [ks=w][row 128][32], async
        const u16* gq = xqkv + (size_t)(qt * 128 + (l >> 2)) * DQKV + qh * HD + w * 32 + (l & 3) * 8;
#pragma unroll
        for (int i = 0; i < 8; ++i)
            GLOAD_LDS16(gq + (size_t)i * 16 * DQKV, &sm[w * 4096 + i * 512]);
    }
    __syncthreads();
    bf8 qf[4][2];
#pragma unroll
    for (int ks = 0; ks < 4; ++ks)
#pragma unroll
        for (int mt = 0; mt < 2; ++mt)
            qf[ks][mt] = *(const bf8*)&sm[ks * 4096 + (w * 32 + mt * 16 + l15) * 32 + q4 * 8];
    __syncthreads();

    f32x4 O[2][8] = {};
    float plrow[2][4] = {};   // per-lane unnormalized row-sum partials

    u16* ldsK = sm;
    u16* ldsV = sm + 8192;
    u16* ldsP = sm + 16384;
    const int nkt = 2 * qt + 2;
    const float cs = 0.12751744f; // (1/sqrt(128)) * log2(e)

    const u16* gk_base = xqkv + (32 + kh) * HD + w * 32 + (l & 3) * 8;
    const u16* gv_base = vt + (size_t)kh * HD * SEQ + (size_t)((w & 1) * 64 + (l >> 2)) * SEQ + (w >> 1) * 32 + (l & 3) * 8;

    for (int kt = 0; kt < nkt; ++kt) {
        { // stage K: wave w owns k-chunk ks=w  (async, lane-contiguous)
            const u16* gk = gk_base + (size_t)(kt * 64 + (l >> 2)) * DQKV;
#pragma unroll
            for (int i = 0; i < 4; ++i)
                GLOAD_LDS16(gk + (size_t)i * 16 * DQKV, ldsK + w * 2048 + i * 512);
        }
        { // stage V^T: wave w owns pk=w>>1, d-half=(w&1)*64
            const u16* gv = gv_base + kt * 64;
#pragma unroll
            for (int i = 0; i < 4; ++i)
                GLOAD_LDS16(gv + (size_t)i * 16 * SEQ, ldsV + (w >> 1) * 4096 + (w & 1) * 2048 + i * 512);
        }
        __syncthreads();   // drains vmcnt

        // S = Q K^T
        f32x4 S[2][4] = {};
#pragma unroll
        for (int ks = 0; ks < 4; ++ks) {
            bf8 kf[4];
#pragma unroll
            for (int nt = 0; nt < 4; ++nt)
                kf[nt] = *(const bf8*)&ldsK[ks * 2048 + (nt * 16 + l15) * 32 + q4 * 8];
#pragma unroll
            for (int mt = 0; mt < 2; ++mt)
#pragma unroll
                for (int nt = 0; nt < 4; ++nt)
                    S[mt][nt] = __builtin_amdgcn_mfma_f32_16x16x32_bf16(qf[ks][mt], kf[nt], S[mt][nt], 0, 0, 0);
        }

        const bool domask = (kt >= 2 * qt);
#pragma unroll
        for (int mt = 0; mt < 2; ++mt)
#pragma unroll
            for (int r = 0; r < 4; ++r) {
                const int row = qt * 128 + w * 32 + mt * 16 + q4 * 4 + r;
#pragma unroll
                for (int nt = 0; nt < 4; ++nt) {
                    float t = S[mt][nt][r] * cs;
                    if (domask && (kt * 64 + nt * 16 + l15 > row)) t = -1e30f;
                    float p = exp2f(t);
                    plrow[mt][r] += p;
                    ldsP[(w * 32 + mt * 16 + q4 * 4 + r) * PSTR + nt * 16 + l15] = f2bf(p);
                }
            }

        // O += P V   (P rows are wave-private: no barrier needed)
#pragma unroll
        for (int pk = 0; pk < 2; ++pk) {
            bf8 pf[2], vf[8];
#pragma unroll
            for (int mt = 0; mt < 2; ++mt)
                pf[mt] = *(const bf8*)&ldsP[(w * 32 + mt * 16 + l15) * PSTR + pk * 32 + q4 * 8];
#pragma unroll
            for (int nt = 0; nt < 8; ++nt)
                vf[nt] = *(const bf8*)&ldsV[pk * 4096 + (nt * 16 + l15) * 32 + q4 * 8];
#pragma unroll
            for (int mt = 0; mt < 2; ++mt)
#pragma unroll
                for (int nt = 0; nt < 8; ++nt)
                    O[mt][nt] = __builtin_amdgcn_mfma_f32_16x16x32_bf16(pf[mt], vf[nt], O[mt][nt], 0, 0, 0);
        }
        __syncthreads();   // all waves done reading K/V/P before next stage
    }

#pragma unroll
    for (int mt = 0; mt < 2; ++mt)
#pragma unroll
        for (int r = 0; r < 4; ++r) {
            float ls = plrow[mt][r];   // row-sum lives across the 16 lanes of this q4 group
#pragma unroll
            for (int off = 1; off <= 8; off <<= 1)
                ls += __shfl_xor(ls, off, 64);
            const float linv = 1.0f / ls;
            const int row = qt * 128 + w * 32 + mt * 16 + q4 * 4 + r;
#pragma unroll
            for (int nt = 0; nt < 8; ++nt)
                aw[(size_t)row * 4096 + qh * HD + nt * 16 + l15] = f2bf(O[mt][nt][r] * linv);
        }
}

// ---------------- launch ----------------

extern "C" void kernel_launch(void* const* d_in, const int* in_sizes, int n_in,
                              void* d_out, int out_size, void* d_ws, size_t ws_size,
                              hipStream_t stream) {
    const float* hs = (const float*)d_in[0];
    const float* wqkv = (const float*)d_in[1];
    const float* wo = (const float*)d_in[2];
    float* out = (float*)d_out;

    char* ws = (char*)d_ws;
    const size_t oHbf = 0;
    const size_t oWqkvT = oHbf + (size_t)SEQ * HIDDEN * 2;          // 16.78 MB
    const size_t oWoT = oWqkvT + (size_t)DQKV * HIDDEN * 2;         // +50.33 MB
    const size_t oXQKV = oWoT + (size_t)HIDDEN * HIDDEN * 2;        // +33.55 MB
    const size_t oVT = oXQKV + (size_t)SEQ * DQKV * 2;              // +25.17 MB
    const size_t oAW = oVT + (size_t)8 * HD * SEQ * 2;              // +4.19 MB
    const size_t total = oAW + (size_t)SEQ * HIDDEN * 2;            // +16.78 MB = 146.8 MB
    if (ws_size < total) return;

    u16* Hbf = (u16*)(ws + oHbf);
    u16* WqkvT = (u16*)(ws + oWqkvT);
    u16* WoT = (u16*)(ws + oWoT);
    u16* XQKV = (u16*)(ws + oXQKV);
    u16* VT = (u16*)(ws + oVT);
    u16* AW = (u16*)(ws + oAW);

    convert_bf16_kernel<<<(SEQ * HIDDEN) / 1024, 256, 0, stream>>>(hs, Hbf);
    transpose_w_kernel<<<(HIDDEN / 64) * (DQKV / 64), 256, 0, stream>>>(wqkv, WqkvT, HIDDEN, DQKV);
    transpose_w_kernel<<<(HIDDEN / 64) * (HIDDEN / 64), 256, 0, stream>>>(wo, WoT, HIDDEN, HIDDEN);
    gemm8p_kernel<256, 192, 0><<<8 * 32, 512, 0, stream>>>(Hbf, WqkvT, XQKV, nullptr);  // 256 blocks
    rope_kernel<<<SEQ * 10, 256, 0, stream>>>(XQKV);
    transpose_v_kernel<<<8 * 64, 256, 0, stream>>>(XQKV, VT);
    attn_kernel<<<512, 256, 0, stream>>>(XQKV, VT, AW);
    gemm8p_kernel<128, 256, 1><<<16 * 16, 512, 0, stream>>>(AW, WoT, nullptr, out);     // 256 blocks
}